// Round 7
// baseline (235.141 us; speedup 1.0000x reference)
//
#include <hip/hip_runtime.h>
#include <math.h>

#define BATCH 131072
#define NSTEPS 256
#define LOGLO -16.0f
#define LOGSPAN 26.0f
#define LGN 10
#define NPTS 1024          // (1 << LGN)
#define WIN 768            // staged window entries per step row (6 KB)

using f32x2 = __attribute__((ext_vector_type(2))) float;

__device__ __forceinline__ float fast_exp(float x) {
    return __builtin_amdgcn_exp2f(x * 1.44269504088896340736f);
}
__device__ __forceinline__ float fast_rcp(float x) {
    return __builtin_amdgcn_rcpf(x);
}
__device__ __forceinline__ float sigmoidf_fast(float x) {
    return fast_rcp(1.0f + fast_exp(-x));
}

#define REP32(M) M(0) M(1) M(2) M(3) M(4) M(5) M(6) M(7) \
                 M(8) M(9) M(10) M(11) M(12) M(13) M(14) M(15) \
                 M(16) M(17) M(18) M(19) M(20) M(21) M(22) M(23) \
                 M(24) M(25) M(26) M(27) M(28) M(29) M(30) M(31)

#define REP8(M) M(0) M(1) M(2) M(3) M(4) M(5) M(6) M(7)

// Shared MLP+tangent body (see R4). Produces h and pre-sigmoid tangent acc.
#define MLP_BODY(W1r, B1, W2r, B2, W3r, b3v, t, s, sd, H, HACC) \
    { \
        const float __t = (t), __s = (s), __sd = (sd); \
        f32x2 acc2 = {(b3v), 0.0f}; \
        REP32(MLP_L1) \
        REP32(MLP_ROW) \
        H = sigmoidf_fast(acc2.x); \
        HACC = acc2.y; \
    }

#define MLP_L1(j) f32x2 at##j; { \
    const float2 wv = W1r[j]; \
    const float z  = fmaf(wv.x, __t, fmaf(wv.y, __s, B1[j])); \
    const float zd = wv.y * __sd; \
    const float sg = sigmoidf_fast(z); \
    const float da = sg * (1.0f + z * (1.0f - sg)); \
    at##j = (f32x2){z * sg, da * zd}; }

#define MLP_ROW(j) { \
    const float4 q0 = W2r[(j) * 8 + 0]; \
    const float4 q1 = W2r[(j) * 8 + 1]; \
    const float4 q2 = W2r[(j) * 8 + 2]; \
    const float4 q3 = W2r[(j) * 8 + 3]; \
    const float4 q4 = W2r[(j) * 8 + 4]; \
    const float4 q5 = W2r[(j) * 8 + 5]; \
    const float4 q6 = W2r[(j) * 8 + 6]; \
    const float4 q7 = W2r[(j) * 8 + 7]; \
    f32x2 zza = {B2[j], 0.0f}; \
    f32x2 zzb = {0.0f, 0.0f}; \
    zza += (f32x2){q0.x, q0.x} * at0;  zzb += (f32x2){q0.y, q0.y} * at1; \
    zza += (f32x2){q0.z, q0.z} * at2;  zzb += (f32x2){q0.w, q0.w} * at3; \
    zza += (f32x2){q1.x, q1.x} * at4;  zzb += (f32x2){q1.y, q1.y} * at5; \
    zza += (f32x2){q1.z, q1.z} * at6;  zzb += (f32x2){q1.w, q1.w} * at7; \
    zza += (f32x2){q2.x, q2.x} * at8;  zzb += (f32x2){q2.y, q2.y} * at9; \
    zza += (f32x2){q2.z, q2.z} * at10; zzb += (f32x2){q2.w, q2.w} * at11; \
    zza += (f32x2){q3.x, q3.x} * at12; zzb += (f32x2){q3.y, q3.y} * at13; \
    zza += (f32x2){q3.z, q3.z} * at14; zzb += (f32x2){q3.w, q3.w} * at15; \
    zza += (f32x2){q4.x, q4.x} * at16; zzb += (f32x2){q4.y, q4.y} * at17; \
    zza += (f32x2){q4.z, q4.z} * at18; zzb += (f32x2){q4.w, q4.w} * at19; \
    zza += (f32x2){q5.x, q5.x} * at20; zzb += (f32x2){q5.y, q5.y} * at21; \
    zza += (f32x2){q5.z, q5.z} * at22; zzb += (f32x2){q5.w, q5.w} * at23; \
    zza += (f32x2){q6.x, q6.x} * at24; zzb += (f32x2){q6.y, q6.y} * at25; \
    zza += (f32x2){q6.z, q6.z} * at26; zzb += (f32x2){q6.w, q6.w} * at27; \
    zza += (f32x2){q7.x, q7.x} * at28; zzb += (f32x2){q7.y, q7.y} * at29; \
    zza += (f32x2){q7.z, q7.z} * at30; zzb += (f32x2){q7.w, q7.w} * at31; \
    const f32x2 zzt = zza + zzb; \
    const float zv  = zzt.x; \
    const float sg  = sigmoidf_fast(zv); \
    const float da  = sg * (1.0f + zv * (1.0f - sg)); \
    const float w3  = W3r[j]; \
    acc2 += (f32x2){w3, w3} * (f32x2){zv * sg, da * zzt.y}; \
}

// ---------------------------------------------------------------------------
// Kernel 1: per-step lookup table T[st][k] = {h, dh/ds} at s = 2^(lo+k*dx).
// ---------------------------------------------------------------------------
__global__ __launch_bounds__(256) void table_kernel(
    const float* __restrict__ ts,
    const float* __restrict__ W1, const float* __restrict__ b1,
    const float* __restrict__ W2, const float* __restrict__ b2,
    const float* __restrict__ W3, const float* __restrict__ b3,
    float2* __restrict__ T, float lo, float dx)
{
    __shared__ __align__(16) float sW1[64];
    __shared__ float sb1[32];
    __shared__ __align__(16) float sW2[1024];
    __shared__ float sb2[32];
    __shared__ float sW3[32];
    __shared__ float sb3[1];

    const int tid = threadIdx.x;
    for (int i = tid; i < 1024; i += 256) sW2[i] = W2[i];
    if (tid < 64) sW1[tid] = W1[tid];
    if (tid < 32) { sb1[tid] = b1[tid]; sb2[tid] = b2[tid]; sW3[tid] = W3[tid]; }
    if (tid == 0) sb3[0] = b3[0];
    __syncthreads();

    const float2* W1r = (const float2*)sW1;
    const float*  B1  = sb1;
    const float4* W2r = (const float4*)sW2;
    const float*  B2  = sb2;
    const float*  W3r = sW3;
    const float   b3v = sb3[0];

    const int gid = blockIdx.x * 256 + tid;
    const int st = gid >> LGN;
    const int k  = gid & (NPTS - 1);

    const float t = ts[st];
    const float s = __builtin_amdgcn_exp2f(fmaf((float)k, dx, lo));

    float h, hacc;
    MLP_BODY(W1r, B1, W2r, B2, W3r, b3v, t, s, 1.0f, h, hacc)

    const float hp = h * (1.0f - h) * hacc;   // dh/ds
    T[gid] = make_float2(h, hp);
}

// ---------------------------------------------------------------------------
// Kernel 2: SDE path integration. Per 8-step chunk: stage the hot 768-entry
// window of each step's table row into LDS (coalesced), then do the random
// interp gathers from LDS. log2(s_t) ~ N(0.7213*t, (1.4427*sqrt(t))^2), so
// the window covers >6 sigma at every t; out-of-window lanes (P~1e-9) fall
// back to a global gather from the full table.
// ---------------------------------------------------------------------------
__global__ __launch_bounds__(256, 2) void path_kernel(
    const float* __restrict__ noise,   // (NSTEPS, BATCH)
    const float* __restrict__ ts,      // (NSTEPS+1)
    const float* __restrict__ wq,      // scalar
    const float2* __restrict__ T,      // (NSTEPS, NPTS)
    float lo, float invdx,
    float* __restrict__ out)           // (BATCH)
{
    __shared__ float2 sdt[NSTEPS];
    __shared__ float  sts_[NSTEPS];
    __shared__ __align__(16) float2 Lwin[8][WIN];   // 48 KB

    const int tid = threadIdx.x;
    if (tid < NSTEPS) {
        const float t0 = ts[tid];
        const float dtv = ts[tid + 1] - t0;
        sts_[tid] = t0;
        sdt[tid] = make_float2(dtv, __builtin_sqrtf(dtv));
    }
    __syncthreads();

    const int gid = blockIdx.x * 256 + tid;
    const float* np_ = noise + gid;
    const float umax = (float)(NPTS - 1) - 0.001f;

    float s   = 1.0f;
    float pnl = 0.0f;

    // preload chunk 0 noise
    #define NLD0(k) float n##k = np_[(size_t)(k) * BATCH];
    REP8(NLD0)
    #undef NLD0

    #pragma unroll 1
    for (int c = 0; c < NSTEPS / 8; ++c) {
        const int base = c * 8;

        // window start per row (identical computation in every thread)
        #define K0(r) int k0##r; { \
            const float mx = 0.72134752f * sts_[base + r]; \
            int kk = (int)((mx - lo) * invdx) - (WIN / 2); \
            kk &= ~1;  /* keep 16B alignment of the slice */ \
            k0##r = min(max(kk, 0), NPTS - WIN); }
        REP8(K0)
        #undef K0

        __syncthreads();   // previous chunk's consumers are done with Lwin

        // stage 8 rows x 768 entries (384 float4 per row = 256 + 128)
        #define STG(r) { \
            const float4* s4 = (const float4*)(T + ((size_t)(base + r) << LGN) + k0##r); \
            float4* d4 = (float4*)(&Lwin[r][0]); \
            d4[tid] = s4[tid]; \
            if (tid < 128) d4[tid + 256] = s4[tid + 256]; }
        REP8(STG)
        #undef STG

        __syncthreads();   // windows ready

        // prefetch next chunk's noise (in flight during compute)
        const float* nb = np_ + ((size_t)base + 8) * BATCH;
        const bool more = (c < NSTEPS / 8 - 1);
        #define NPF(k) const float m##k = more ? nb[(size_t)(k) * BATCH] : 0.0f;
        REP8(NPF)
        #undef NPF

        // s-chain + issue all LDS gathers
        #define CH(k) \
            const float2 dts##k = sdt[base + k]; \
            const float dW##k   = n##k * dts##k.y; \
            const float mil##k  = 0.5f * fmaf(dW##k, dW##k, -dts##k.x); \
            const float sum1##k = dts##k.x + dW##k; \
            const float sv##k   = s; \
            s = fmaf(s, sum1##k + mil##k, s); \
            const float x##k = __builtin_amdgcn_logf(sv##k); \
            const float u##k = fminf(fmaxf((x##k - lo) * invdx, 0.0f), umax); \
            const int   i0##k = (int)u##k; \
            const float f##k  = u##k - (float)i0##k; \
            const int   li##k = i0##k - k0##k; \
            float2 e0##k, e1##k; \
            if (__builtin_expect((unsigned)li##k < (WIN - 1), 1)) { \
                e0##k = Lwin[k][li##k]; \
                e1##k = Lwin[k][li##k + 1]; \
            } else { \
                const float2* Tr = T + ((size_t)(base + k) << LGN); \
                e0##k = Tr[i0##k]; \
                e1##k = Tr[i0##k + 1]; \
            }
        REP8(CH)
        #undef CH

        // consume into pnl
        #define PN(k) { \
            const float h  = fmaf(f##k, e1##k.x - e0##k.x, e0##k.x); \
            const float hp = fmaf(f##k, e1##k.y - e0##k.y, e0##k.y); \
            const float g1  = sv##k * h; \
            const float dg1 = fmaf(sv##k * sv##k, hp, g1); \
            pnl = fmaf(dg1, mil##k, fmaf(g1, sum1##k, pnl)); }
        REP8(PN)
        #undef PN

        // rotate prefetched noise
        #define NRT(k) n##k = m##k;
        REP8(NRT)
        #undef NRT
    }

    const float z = fmaxf(0.0f, s - 3.0f);
    const float d = z - pnl - wq[0];
    out[gid] = d * d;
}

// ---------------------------------------------------------------------------
// Fallback: direct per-thread MLP evaluation (R4 kernel) if ws too small.
// ---------------------------------------------------------------------------
__global__ __launch_bounds__(256, 3) void deep_hedging_direct(
    const float* __restrict__ noise, const float* __restrict__ ts,
    const float* __restrict__ w,
    const float* __restrict__ W1, const float* __restrict__ b1,
    const float* __restrict__ W2, const float* __restrict__ b2,
    const float* __restrict__ W3, const float* __restrict__ b3,
    float* __restrict__ out)
{
    __shared__ __align__(16) float sW1[64];
    __shared__ float sb1[32];
    __shared__ __align__(16) float sW2[1024];
    __shared__ float sb2[32];
    __shared__ float sW3[32];
    __shared__ float sb3w[2];
    __shared__ float sts[NSTEPS + 1];

    const int tid = threadIdx.x;
    for (int i = tid; i < 1024; i += 256) sW2[i] = W2[i];
    if (tid < 64) sW1[tid] = W1[tid];
    if (tid < 32) { sb1[tid] = b1[tid]; sb2[tid] = b2[tid]; sW3[tid] = W3[tid]; }
    if (tid == 0) { sb3w[0] = b3[0]; sb3w[1] = w[0]; }
    for (int i = tid; i < NSTEPS + 1; i += 256) sts[i] = ts[i];
    __syncthreads();

    const int gid = blockIdx.x * 256 + tid;
    const float* np_ = noise + gid;

    float s   = 1.0f;
    float pnl = 0.0f;
    const float b3v = sb3w[0];
    const float wv_ = sb3w[1];

    #pragma unroll 1
    for (int st = 0; st < NSTEPS; ++st) {
        int zr = 0;
        asm volatile("" : "+v"(zr));   // block LICM of weight loads
        const float2* W1r = (const float2*)sW1 + zr;
        const float*  B1  = sb1 + zr;
        const float4* W2r = (const float4*)sW2 + zr;
        const float*  B2  = sb2 + zr;
        const float*  W3r = sW3 + zr;

        const float t  = sts[st];
        const float dt = sts[st + 1] - t;
        const float dW = np_[(size_t)st * BATCH] * __builtin_sqrtf(dt);
        const float sd = s;

        float h, hacc;
        MLP_BODY(W1r, B1, W2r, B2, W3r, b3v, t, s, sd, h, hacc)
        const float hd = h * (1.0f - h) * hacc;

        const float mil = 0.5f * (dW * dW - dt);
        const float g1  = s * h;
        const float dg1 = fmaf(sd, h, s * hd);
        const float snew = s + s * dt + s * dW + sd * mil;
        pnl = pnl + g1 * dt + g1 * dW + dg1 * mil;
        s = snew;
    }

    const float z = fmaxf(0.0f, s - 3.0f);
    const float d = z - pnl - wv_;
    out[gid] = d * d;
}

extern "C" void kernel_launch(void* const* d_in, const int* in_sizes, int n_in,
                              void* d_out, int out_size, void* d_ws, size_t ws_size,
                              hipStream_t stream) {
    const float* noise = (const float*)d_in[0];
    const float* ts    = (const float*)d_in[1];
    const float* w     = (const float*)d_in[2];
    const float* W1    = (const float*)d_in[3];
    const float* b1    = (const float*)d_in[4];
    const float* W2    = (const float*)d_in[5];
    const float* b2    = (const float*)d_in[6];
    const float* W3    = (const float*)d_in[7];
    const float* b3    = (const float*)d_in[8];
    float* out = (float*)d_out;

    const size_t need = (size_t)NSTEPS * NPTS * sizeof(float2);   // 2 MB

    if (ws_size >= need) {
        const float dx = LOGSPAN / (float)NPTS;
        const float invdx = (float)NPTS / LOGSPAN;
        float2* T = (float2*)d_ws;

        dim3 tb(256), tg((NSTEPS * NPTS) / 256);
        table_kernel<<<tg, tb, 0, stream>>>(ts, W1, b1, W2, b2, W3, b3,
                                            T, LOGLO, dx);
        dim3 pb(256), pg(BATCH / 256);
        path_kernel<<<pg, pb, 0, stream>>>(noise, ts, w, T, LOGLO,
                                           invdx, out);
    } else {
        dim3 grid(BATCH / 256), block(256);
        deep_hedging_direct<<<grid, block, 0, stream>>>(noise, ts, w, W1, b1,
                                                        W2, b2, W3, b3, out);
    }
}

// Round 8
// 77.263 us; speedup vs baseline: 3.0434x; 3.0434x over previous
//
#include <hip/hip_runtime.h>
#include <hip/hip_fp16.h>
#include <math.h>

#define BATCH 131072
#define NSTEPS 256
#define LOGLO -16.0f
#define LOGSPAN 26.0f
#define LGN 10
#define NPTS 1024          // (1 << LGN)

using f32x2 = __attribute__((ext_vector_type(2))) float;

__device__ __forceinline__ float fast_exp(float x) {
    return __builtin_amdgcn_exp2f(x * 1.44269504088896340736f);
}
__device__ __forceinline__ float fast_rcp(float x) {
    return __builtin_amdgcn_rcpf(x);
}
__device__ __forceinline__ float sigmoidf_fast(float x) {
    return fast_rcp(1.0f + fast_exp(-x));
}

#define REP32(M) M(0) M(1) M(2) M(3) M(4) M(5) M(6) M(7) \
                 M(8) M(9) M(10) M(11) M(12) M(13) M(14) M(15) \
                 M(16) M(17) M(18) M(19) M(20) M(21) M(22) M(23) \
                 M(24) M(25) M(26) M(27) M(28) M(29) M(30) M(31)

#define REP8(M) M(0) M(1) M(2) M(3) M(4) M(5) M(6) M(7)

// Shared MLP+tangent body (see R4). Produces h and pre-sigmoid tangent acc.
#define MLP_BODY(W1r, B1, W2r, B2, W3r, b3v, t, s, sd, H, HACC) \
    { \
        const float __t = (t), __s = (s), __sd = (sd); \
        f32x2 acc2 = {(b3v), 0.0f}; \
        REP32(MLP_L1) \
        REP32(MLP_ROW) \
        H = sigmoidf_fast(acc2.x); \
        HACC = acc2.y; \
    }

#define MLP_L1(j) f32x2 at##j; { \
    const float2 wv = W1r[j]; \
    const float z  = fmaf(wv.x, __t, fmaf(wv.y, __s, B1[j])); \
    const float zd = wv.y * __sd; \
    const float sg = sigmoidf_fast(z); \
    const float da = sg * (1.0f + z * (1.0f - sg)); \
    at##j = (f32x2){z * sg, da * zd}; }

#define MLP_ROW(j) { \
    const float4 q0 = W2r[(j) * 8 + 0]; \
    const float4 q1 = W2r[(j) * 8 + 1]; \
    const float4 q2 = W2r[(j) * 8 + 2]; \
    const float4 q3 = W2r[(j) * 8 + 3]; \
    const float4 q4 = W2r[(j) * 8 + 4]; \
    const float4 q5 = W2r[(j) * 8 + 5]; \
    const float4 q6 = W2r[(j) * 8 + 6]; \
    const float4 q7 = W2r[(j) * 8 + 7]; \
    f32x2 zza = {B2[j], 0.0f}; \
    f32x2 zzb = {0.0f, 0.0f}; \
    zza += (f32x2){q0.x, q0.x} * at0;  zzb += (f32x2){q0.y, q0.y} * at1; \
    zza += (f32x2){q0.z, q0.z} * at2;  zzb += (f32x2){q0.w, q0.w} * at3; \
    zza += (f32x2){q1.x, q1.x} * at4;  zzb += (f32x2){q1.y, q1.y} * at5; \
    zza += (f32x2){q1.z, q1.z} * at6;  zzb += (f32x2){q1.w, q1.w} * at7; \
    zza += (f32x2){q2.x, q2.x} * at8;  zzb += (f32x2){q2.y, q2.y} * at9; \
    zza += (f32x2){q2.z, q2.z} * at10; zzb += (f32x2){q2.w, q2.w} * at11; \
    zza += (f32x2){q3.x, q3.x} * at12; zzb += (f32x2){q3.y, q3.y} * at13; \
    zza += (f32x2){q3.z, q3.z} * at14; zzb += (f32x2){q3.w, q3.w} * at15; \
    zza += (f32x2){q4.x, q4.x} * at16; zzb += (f32x2){q4.y, q4.y} * at17; \
    zza += (f32x2){q4.z, q4.z} * at18; zzb += (f32x2){q4.w, q4.w} * at19; \
    zza += (f32x2){q5.x, q5.x} * at20; zzb += (f32x2){q5.y, q5.y} * at21; \
    zza += (f32x2){q5.z, q5.z} * at22; zzb += (f32x2){q5.w, q5.w} * at23; \
    zza += (f32x2){q6.x, q6.x} * at24; zzb += (f32x2){q6.y, q6.y} * at25; \
    zza += (f32x2){q6.z, q6.z} * at26; zzb += (f32x2){q6.w, q6.w} * at27; \
    zza += (f32x2){q7.x, q7.x} * at28; zzb += (f32x2){q7.y, q7.y} * at29; \
    zza += (f32x2){q7.z, q7.z} * at30; zzb += (f32x2){q7.w, q7.w} * at31; \
    const f32x2 zzt = zza + zzb; \
    const float zv  = zzt.x; \
    const float sg  = sigmoidf_fast(zv); \
    const float da  = sg * (1.0f + zv * (1.0f - sg)); \
    const float w3  = W3r[j]; \
    acc2 += (f32x2){w3, w3} * (f32x2){zv * sg, da * zzt.y}; \
}

// ---------------------------------------------------------------------------
// Kernel 1: per-step lookup table T[st][k] = half2{h, q} at s = 2^(lo+k*dx),
// where q = s * dh/ds = (1/ln2) * dh/dlog2(s).  q is O(1)-bounded (raw dh/ds
// would overflow fp16 at small s) and is exactly what the Milstein term needs:
// dg1 = s*(h + q).
// ---------------------------------------------------------------------------
__global__ __launch_bounds__(256) void table_kernel(
    const float* __restrict__ ts,
    const float* __restrict__ W1, const float* __restrict__ b1,
    const float* __restrict__ W2, const float* __restrict__ b2,
    const float* __restrict__ W3, const float* __restrict__ b3,
    __half2* __restrict__ T, float lo, float dx)
{
    __shared__ __align__(16) float sW1[64];
    __shared__ float sb1[32];
    __shared__ __align__(16) float sW2[1024];
    __shared__ float sb2[32];
    __shared__ float sW3[32];
    __shared__ float sb3[1];

    const int tid = threadIdx.x;
    for (int i = tid; i < 1024; i += 256) sW2[i] = W2[i];
    if (tid < 64) sW1[tid] = W1[tid];
    if (tid < 32) { sb1[tid] = b1[tid]; sb2[tid] = b2[tid]; sW3[tid] = W3[tid]; }
    if (tid == 0) sb3[0] = b3[0];
    __syncthreads();

    const float2* W1r = (const float2*)sW1;
    const float*  B1  = sb1;
    const float4* W2r = (const float4*)sW2;
    const float*  B2  = sb2;
    const float*  W3r = sW3;
    const float   b3v = sb3[0];

    const int gid = blockIdx.x * 256 + tid;
    const int st = gid >> LGN;
    const int k  = gid & (NPTS - 1);

    const float t = ts[st];
    const float s = __builtin_amdgcn_exp2f(fmaf((float)k, dx, lo));

    float h, hacc;
    MLP_BODY(W1r, B1, W2r, B2, W3r, b3v, t, s, 1.0f, h, hacc)

    const float q = h * (1.0f - h) * hacc * s;   // s * dh/ds
    T[gid] = __floats2half2_rn(h, q);
}

// ---------------------------------------------------------------------------
// Kernel 2: SDE path integration (R6 ILP structure: s-recurrence runs ahead,
// all 16 table gathers per 8-step chunk issued before any is consumed).
// ---------------------------------------------------------------------------
__global__ __launch_bounds__(256, 2) void path_kernel(
    const float* __restrict__ noise,   // (NSTEPS, BATCH)
    const float* __restrict__ ts,      // (NSTEPS+1)
    const float* __restrict__ wq,      // scalar
    const __half2* __restrict__ T,     // (NSTEPS, NPTS)
    float lo, float invdx,
    float* __restrict__ out)           // (BATCH)
{
    __shared__ float2 sdt[NSTEPS];
    const int tid = threadIdx.x;
    if (tid < NSTEPS) {
        const float dtv = ts[tid + 1] - ts[tid];
        sdt[tid] = make_float2(dtv, __builtin_sqrtf(dtv));
    }
    __syncthreads();

    const int gid = blockIdx.x * 256 + tid;
    const float* np_ = noise + gid;
    const float umax = (float)(NPTS - 1) - 0.001f;

    float s   = 1.0f;
    float pnl = 0.0f;

    // preload chunk 0 noise
    #define NLD0(k) float n##k = np_[(size_t)(k) * BATCH];
    REP8(NLD0)
    #undef NLD0

    #pragma unroll 1
    for (int c = 0; c < NSTEPS / 8; ++c) {
        const int base = c * 8;

        // prefetch next chunk's noise (independent loads, issued early)
        const float* nb = np_ + ((size_t)base + 8) * BATCH;
        const bool more = (c < NSTEPS / 8 - 1);
        #define NPF(k) const float m##k = more ? nb[(size_t)(k) * BATCH] : 0.0f;
        REP8(NPF)
        #undef NPF

        // s-chain (cheap, serial) + issue all 16 table gathers
        #define CH(k) \
            const float2 dts##k = sdt[base + k]; \
            const float dW##k   = n##k * dts##k.y; \
            const float mil##k  = 0.5f * fmaf(dW##k, dW##k, -dts##k.x); \
            const float sum1##k = dts##k.x + dW##k; \
            const float sv##k   = s; \
            s = fmaf(s, sum1##k + mil##k, s); \
            const float x##k = __builtin_amdgcn_logf(sv##k); \
            const float u##k = fminf(fmaxf((x##k - lo) * invdx, 0.0f), umax); \
            const int   i0##k = (int)u##k; \
            const float f##k  = u##k - (float)i0##k; \
            const __half2* Tr##k = T + ((size_t)(base + k) << LGN); \
            const __half2 e0##k = Tr##k[i0##k]; \
            const __half2 e1##k = Tr##k[i0##k + 1];
        REP8(CH)
        #undef CH

        // consume gathers into pnl
        #define PN(k) { \
            const float2 a0 = __half22float2(e0##k); \
            const float2 a1 = __half22float2(e1##k); \
            const float h  = fmaf(f##k, a1.x - a0.x, a0.x); \
            const float q  = fmaf(f##k, a1.y - a0.y, a0.y); \
            const float g1  = sv##k * h; \
            const float dg1 = fmaf(sv##k, q, g1); \
            pnl = fmaf(dg1, mil##k, fmaf(g1, sum1##k, pnl)); }
        REP8(PN)
        #undef PN

        // rotate prefetched noise into place
        #define NRT(k) n##k = m##k;
        REP8(NRT)
        #undef NRT
    }

    const float z = fmaxf(0.0f, s - 3.0f);
    const float d = z - pnl - wq[0];
    out[gid] = d * d;
}

// ---------------------------------------------------------------------------
// Fallback: direct per-thread MLP evaluation (R4 kernel) if ws too small.
// ---------------------------------------------------------------------------
__global__ __launch_bounds__(256, 3) void deep_hedging_direct(
    const float* __restrict__ noise, const float* __restrict__ ts,
    const float* __restrict__ w,
    const float* __restrict__ W1, const float* __restrict__ b1,
    const float* __restrict__ W2, const float* __restrict__ b2,
    const float* __restrict__ W3, const float* __restrict__ b3,
    float* __restrict__ out)
{
    __shared__ __align__(16) float sW1[64];
    __shared__ float sb1[32];
    __shared__ __align__(16) float sW2[1024];
    __shared__ float sb2[32];
    __shared__ float sW3[32];
    __shared__ float sb3w[2];
    __shared__ float sts[NSTEPS + 1];

    const int tid = threadIdx.x;
    for (int i = tid; i < 1024; i += 256) sW2[i] = W2[i];
    if (tid < 64) sW1[tid] = W1[tid];
    if (tid < 32) { sb1[tid] = b1[tid]; sb2[tid] = b2[tid]; sW3[tid] = W3[tid]; }
    if (tid == 0) { sb3w[0] = b3[0]; sb3w[1] = w[0]; }
    for (int i = tid; i < NSTEPS + 1; i += 256) sts[i] = ts[i];
    __syncthreads();

    const int gid = blockIdx.x * 256 + tid;
    const float* np_ = noise + gid;

    float s   = 1.0f;
    float pnl = 0.0f;
    const float b3v = sb3w[0];
    const float wv_ = sb3w[1];

    #pragma unroll 1
    for (int st = 0; st < NSTEPS; ++st) {
        int zr = 0;
        asm volatile("" : "+v"(zr));   // block LICM of weight loads
        const float2* W1r = (const float2*)sW1 + zr;
        const float*  B1  = sb1 + zr;
        const float4* W2r = (const float4*)sW2 + zr;
        const float*  B2  = sb2 + zr;
        const float*  W3r = sW3 + zr;

        const float t  = sts[st];
        const float dt = sts[st + 1] - t;
        const float dW = np_[(size_t)st * BATCH] * __builtin_sqrtf(dt);
        const float sd = s;

        float h, hacc;
        MLP_BODY(W1r, B1, W2r, B2, W3r, b3v, t, s, sd, h, hacc)
        const float hd = h * (1.0f - h) * hacc;

        const float mil = 0.5f * (dW * dW - dt);
        const float g1  = s * h;
        const float dg1 = fmaf(sd, h, s * hd);
        const float snew = s + s * dt + s * dW + sd * mil;
        pnl = pnl + g1 * dt + g1 * dW + dg1 * mil;
        s = snew;
    }

    const float z = fmaxf(0.0f, s - 3.0f);
    const float d = z - pnl - wv_;
    out[gid] = d * d;
}

extern "C" void kernel_launch(void* const* d_in, const int* in_sizes, int n_in,
                              void* d_out, int out_size, void* d_ws, size_t ws_size,
                              hipStream_t stream) {
    const float* noise = (const float*)d_in[0];
    const float* ts    = (const float*)d_in[1];
    const float* w     = (const float*)d_in[2];
    const float* W1    = (const float*)d_in[3];
    const float* b1    = (const float*)d_in[4];
    const float* W2    = (const float*)d_in[5];
    const float* b2    = (const float*)d_in[6];
    const float* W3    = (const float*)d_in[7];
    const float* b3    = (const float*)d_in[8];
    float* out = (float*)d_out;

    const size_t need = (size_t)NSTEPS * NPTS * sizeof(__half2);   // 1 MB

    if (ws_size >= need) {
        const float dx = LOGSPAN / (float)NPTS;
        const float invdx = (float)NPTS / LOGSPAN;
        __half2* T = (__half2*)d_ws;

        dim3 tb(256), tg((NSTEPS * NPTS) / 256);
        table_kernel<<<tg, tb, 0, stream>>>(ts, W1, b1, W2, b2, W3, b3,
                                            T, LOGLO, dx);
        dim3 pb(256), pg(BATCH / 256);
        path_kernel<<<pg, pb, 0, stream>>>(noise, ts, w, T, LOGLO,
                                           invdx, out);
    } else {
        dim3 grid(BATCH / 256), block(256);
        deep_hedging_direct<<<grid, block, 0, stream>>>(noise, ts, w, W1, b1,
                                                        W2, b2, W3, b3, out);
    }
}